// Round 4
// baseline (885.540 us; speedup 1.0000x reference)
//
#include <hip/hip_runtime.h>
#include <hip/hip_bf16.h>
#include <math.h>

// Node classifier: KProp(K=2, gcn_norm) -> SAGEConv(64->64)+selu -> SAGEConv(64->40) -> softmax
// N=100000, E=1600000, D=H=64, C=40. All fp32.
//
// R3 = R2 with the bcnt-zeroing bug fixed (deg and bcnt are NOT contiguous in
// the carve layout; zero them with separate launches).
//
//   CSR build via 2-level bucket sort (dense write streams, no 4B scatter thrash):
//     count_scatter: deg atomics + (src,dst) -> 782 coarse buckets (dst>>7), fixed cap
//     scan -> row_ptr ; bucket_fill: LDS cursors per bucket, fine scatter into
//     the bucket's contiguous csr window.
//   Then (linearity reorder): p0 = S x ; h = S p0 ; [t1|r1] = h@[Wl1|Wr1] ;
//   h1 = selu(mean(t1)+r1+b1) ; [t2|r2+b2] = h1@[Wl2|Wr2] ; out = softmax(mean(t2)+r2).
//   Prop passes: wave per node, scalar uniform index loads, 8 gathers in flight.

#define RFL(x) __builtin_amdgcn_readfirstlane(x)
#define BSHIFT 7
#define BSZ 128   // nodes per bucket

// ---------------- CSR build ----------------

__global__ void zero_int_kernel(int* __restrict__ p, int n) {
    int i = blockIdx.x * blockDim.x + threadIdx.x;
    if (i < n) p[i] = 0;
}

// deg count + coarse bucket scatter in one edge pass
__global__ void count_scatter_kernel(const int* __restrict__ src, const int* __restrict__ dst,
                                     int* __restrict__ deg, int* __restrict__ bcnt,
                                     int2* __restrict__ temp, int e, int cap) {
    int i = blockIdx.x * blockDim.x + threadIdx.x;
    if (i >= e) return;
    int s = src[i];
    int d = dst[i];
    atomicAdd(&deg[d], 1);
    int b = d >> BSHIFT;
    int p = atomicAdd(&bcnt[b], 1);
    if (p < cap) temp[(size_t)b * cap + p] = make_int2(s, d);
}

__global__ __launch_bounds__(1024) void scan1_kernel(const int* __restrict__ deg,
                                                     int* __restrict__ incl,
                                                     int* __restrict__ bsum, int n) {
    __shared__ int tmp[1024];
    int t = threadIdx.x;
    int gi = blockIdx.x * 1024 + t;
    int v = (gi < n) ? deg[gi] : 0;
    tmp[t] = v;
    __syncthreads();
    for (int off = 1; off < 1024; off <<= 1) {
        int u = (t >= off) ? tmp[t - off] : 0;
        __syncthreads();
        tmp[t] += u;
        __syncthreads();
    }
    if (gi < n) incl[gi] = tmp[t];
    if (t == 1023) bsum[blockIdx.x] = tmp[1023];
}

__global__ __launch_bounds__(1024) void scan2_kernel(int* __restrict__ bsum, int nb) {
    __shared__ int tmp[1024];
    int t = threadIdx.x;
    int v = (t < nb) ? bsum[t] : 0;
    tmp[t] = v;
    __syncthreads();
    for (int off = 1; off < 1024; off <<= 1) {
        int u = (t >= off) ? tmp[t - off] : 0;
        __syncthreads();
        tmp[t] += u;
        __syncthreads();
    }
    if (t < nb) bsum[t] = tmp[t] - v;   // exclusive
}

__global__ void scan3_kernel(const int* __restrict__ deg, int* __restrict__ row_ptr,
                             const int* __restrict__ bsum,
                             float* __restrict__ dis, float* __restrict__ cnt_inv,
                             int n, int e) {
    int i = blockIdx.x * blockDim.x + threadIdx.x;
    if (i >= n) return;
    int d = deg[i];
    int ex = row_ptr[i] - d + bsum[i >> 10];
    row_ptr[i] = ex;
    float fd = (float)d;
    dis[i] = (d > 0) ? rsqrtf(fd) : 0.0f;
    cnt_inv[i] = 1.0f / fmaxf(fd, 1.0f);
    if (i == 0) row_ptr[n] = e;
}

// One workgroup per bucket: fine scatter into contiguous csr window, cursors in LDS.
__global__ __launch_bounds__(256) void bucket_fill_kernel(const int2* __restrict__ temp,
                                                          const int* __restrict__ bcnt,
                                                          const int* __restrict__ row_ptr,
                                                          int* __restrict__ csr, int n, int cap) {
    __shared__ int cur[BSZ];
    int b = blockIdx.x;
    int nbeg = b << BSHIFT;
    int t = threadIdx.x;
    if (t < BSZ && nbeg + t < n) cur[t] = row_ptr[nbeg + t];
    __syncthreads();
    int cnt = bcnt[b];
    if (cnt > cap) cnt = cap;
    const int2* tb = temp + (size_t)b * cap;
    for (int i = t; i < cnt; i += 256) {
        int2 e = tb[i];
        int pos = atomicAdd(&cur[e.y - nbeg], 1);
        csr[pos] = e.x;
    }
}

// ---------------- propagation (gather, wave per node) ----------------
// FW: feature width of `in` rows. USE_W: weight = dis[src]. EPI: 0 plain scale,
// 1 = selu(acc*sc + r + b), 2 = softmax(acc*sc + r) over 40 cols.
template <int FW, bool USE_W, int EPI>
__global__ __launch_bounds__(256) void prop_kernel(const float* __restrict__ in,
                                                   float* __restrict__ out,
                                                   const int* __restrict__ row_ptr,
                                                   const int* __restrict__ csr_src,
                                                   const float* __restrict__ dis,
                                                   const float* __restrict__ nscale,
                                                   const float* __restrict__ r_add,
                                                   const float* __restrict__ bias,
                                                   int n) {
    int lane = threadIdx.x & 63;
    int node = RFL(blockIdx.x * 4 + (threadIdx.x >> 6));   // wave-uniform SGPR
    if (node >= n) return;
    int beg = row_ptr[node];
    int end = row_ptr[node + 1];
    float acc = 0.0f;
    int j = beg;
    // 8 independent gathers in flight; indices/weights are wave-uniform scalar loads
    for (; j + 8 <= end; j += 8) {
        int s[8];
        float v[8];
#pragma unroll
        for (int q = 0; q < 8; ++q) s[q] = csr_src[j + q];
#pragma unroll
        for (int q = 0; q < 8; ++q) v[q] = in[(size_t)s[q] * FW + lane];
#pragma unroll
        for (int q = 0; q < 8; ++q) acc += USE_W ? dis[s[q]] * v[q] : v[q];
    }
    for (; j + 4 <= end; j += 4) {
        int s[4];
        float v[4];
#pragma unroll
        for (int q = 0; q < 4; ++q) s[q] = csr_src[j + q];
#pragma unroll
        for (int q = 0; q < 4; ++q) v[q] = in[(size_t)s[q] * FW + lane];
#pragma unroll
        for (int q = 0; q < 4; ++q) acc += USE_W ? dis[s[q]] * v[q] : v[q];
    }
    for (; j < end; ++j) {
        int s = csr_src[j];
        float v = in[(size_t)s * FW + lane];
        acc += USE_W ? dis[s] * v : v;
    }
    float sc = nscale[node];
    if (EPI == 0) {
        out[(size_t)node * FW + lane] = acc * sc;
    } else if (EPI == 1) {
        float t = acc * sc + r_add[(size_t)node * 64 + lane] + bias[lane];
        const float scale = 1.0507009873554805f;
        const float alpha = 1.6732632423543772f;
        t = scale * (t > 0.0f ? t : alpha * expm1f(t));
        out[(size_t)node * 64 + lane] = t;
    } else {
        float t = acc * sc + ((lane < 40) ? r_add[(size_t)node * 40 + lane] : 0.0f);
        float x = (lane < 40) ? t : -INFINITY;
        float m = x;
        for (int off = 32; off; off >>= 1) m = fmaxf(m, __shfl_xor(m, off));
        float e = (lane < 40) ? __expf(x - m) : 0.0f;
        float s = e;
        for (int off = 32; off; off >>= 1) s += __shfl_xor(s, off);
        if (lane < 40) out[(size_t)node * 40 + lane] = e / s;
    }
}

// ---------------- tiled GEMM: [outL|outR] = in(64) @ [Wl|Wr] ----------------
template <int OC, int CP>
__global__ __launch_bounds__(256) void gemm_kernel(const float* __restrict__ in,
                                                   const float* __restrict__ Wl,
                                                   const float* __restrict__ Wr,
                                                   const float* __restrict__ bias,
                                                   float* __restrict__ outL,
                                                   float* __restrict__ outR,
                                                   int n, int add_bias) {
    constexpr int HC = OC / 2;
    constexpr int TX = OC / CP;          // col groups
    constexpr int TY = 256 / TX;         // node groups
    constexpr int NPT = 64 / TY;         // nodes per thread
    constexpr int XP = 68;               // 64 + 4 pad
    constexpr int WP = OC + 4;
    __shared__ float sXT[64 * XP];       // [k][node]
    __shared__ float sW[64 * WP];        // [k][c]: c<HC -> Wl, else Wr
    int t = threadIdx.x;
    int blk = blockIdx.x;
    for (int i = 0; i < 16; ++i) {
        int idx = i * 256 + t;
        int nd = idx >> 6;
        int k = idx & 63;
        int ng = blk * 64 + nd;
        float v = in[(size_t)(ng < n ? ng : n - 1) * 64 + k];
        sXT[k * XP + nd] = v;
    }
    for (int i = t; i < 64 * HC; i += 256) {
        int k = i / HC;
        int c = i % HC;
        sW[k * WP + c] = Wl[i];
        sW[k * WP + HC + c] = Wr[i];
    }
    __syncthreads();
    int tx = t % TX;
    int ty = t / TX;
    float acc[NPT][CP];
#pragma unroll
    for (int i = 0; i < NPT; ++i)
#pragma unroll
        for (int c = 0; c < CP; ++c) acc[i][c] = 0.0f;
#pragma unroll 4
    for (int k = 0; k < 64; ++k) {
        float xv[NPT];
#pragma unroll
        for (int i = 0; i < NPT; ++i) xv[i] = sXT[k * XP + ty * NPT + i];
        float wv[CP];
#pragma unroll
        for (int c = 0; c < CP; ++c) wv[c] = sW[k * WP + tx * CP + c];
#pragma unroll
        for (int i = 0; i < NPT; ++i)
#pragma unroll
            for (int c = 0; c < CP; ++c) acc[i][c] += xv[i] * wv[c];
    }
#pragma unroll
    for (int i = 0; i < NPT; ++i) {
        int ng = blk * 64 + ty * NPT + i;
        if (ng >= n) break;
#pragma unroll
        for (int c = 0; c < CP; ++c) {
            int col = tx * CP + c;
            if (col < HC) {
                outL[(size_t)ng * HC + col] = acc[i][c];
            } else {
                float v = acc[i][c] + (add_bias ? bias[col - HC] : 0.0f);
                outR[(size_t)ng * HC + (col - HC)] = v;
            }
        }
    }
}

// ---------------- launch ----------------

extern "C" void kernel_launch(void* const* d_in, const int* in_sizes, int n_in,
                              void* d_out, int out_size, void* d_ws, size_t ws_size,
                              hipStream_t stream) {
    const float* x   = (const float*)d_in[0];
    const float* Wl1 = (const float*)d_in[1];
    const float* Wr1 = (const float*)d_in[2];
    const float* b1  = (const float*)d_in[3];
    const float* Wl2 = (const float*)d_in[4];
    const float* Wr2 = (const float*)d_in[5];
    const float* b2  = (const float*)d_in[6];
    const int* edge_src = (const int*)d_in[7];
    const int* edge_dst = (const int*)d_in[8];
    float* out = (float*)d_out;

    const int N = in_sizes[0] / 64;
    const int E = in_sizes[7];
    const int NB = (N + BSZ - 1) >> BSHIFT;          // buckets
    int cap = E / NB + (E / NB) / 2 + 512;           // bucket capacity (mean + 50% + slack)
    // temp aliases bufC (N*64 floats = N*256 bytes); clamp cap to fit
    size_t bufC_bytes = (size_t)N * 64 * 4;
    int cap_max = (int)(bufC_bytes / ((size_t)NB * 8));
    if (cap > cap_max) cap = cap_max;

    size_t off = 0;
    auto carve = [&](size_t bytes) -> void* {
        void* p = (char*)d_ws + off;
        off = (off + bytes + 255) & ~(size_t)255;
        return p;
    };
    int*   deg     = (int*)carve((size_t)N * 4);
    int*   row_ptr = (int*)carve((size_t)(N + 1) * 4);
    int*   bcnt    = (int*)carve((size_t)NB * 4);
    int*   bsum    = (int*)carve(1024 * 4);
    float* dis     = (float*)carve((size_t)N * 4);
    float* cnt_inv = (float*)carve((size_t)N * 4);
    int*   csr_src = (int*)carve((size_t)E * 4);
    float* bufA    = (float*)carve((size_t)N * 64 * 4);
    float* bufB    = (float*)carve((size_t)N * 64 * 4);
    float* bufC    = (float*)carve(bufC_bytes);
    int2*  temp    = (int2*)bufC;                    // alias: dead before bufC first written
    (void)ws_size;

    const int nb_e256 = (E + 255) / 256;
    const int nb_scan = (N + 1023) / 1024;
    const int nb_node = (N + 3) / 4;     // 4 waves (nodes) per block
    const int nb_gemm = (N + 63) / 64;   // 64 nodes per block

    // CSR build — deg and bcnt are separate carve regions: zero each explicitly.
    zero_int_kernel<<<(N + 255) / 256, 256, 0, stream>>>(deg, N);
    zero_int_kernel<<<(NB + 255) / 256, 256, 0, stream>>>(bcnt, NB);
    count_scatter_kernel<<<nb_e256, 256, 0, stream>>>(edge_src, edge_dst, deg, bcnt, temp, E, cap);
    scan1_kernel<<<nb_scan, 1024, 0, stream>>>(deg, row_ptr, bsum, N);
    scan2_kernel<<<1, 1024, 0, stream>>>(bsum, nb_scan);
    scan3_kernel<<<(N + 255) / 256, 256, 0, stream>>>(deg, row_ptr, bsum, dis, cnt_inv, N, E);
    bucket_fill_kernel<<<NB, 256, 0, stream>>>(temp, bcnt, row_ptr, csr_src, N, cap);

    // KProp x2: h = S (S x)
    prop_kernel<64, true, 0><<<nb_node, 256, 0, stream>>>(x,    bufA, row_ptr, csr_src, dis, dis, nullptr, nullptr, N);
    prop_kernel<64, true, 0><<<nb_node, 256, 0, stream>>>(bufA, bufB, row_ptr, csr_src, dis, dis, nullptr, nullptr, N);
    // [t1|r1] = h @ [Wl1|Wr1]  (t1 -> bufA, r1 -> bufC)
    gemm_kernel<128, 8><<<nb_gemm, 256, 0, stream>>>(bufB, Wl1, Wr1, nullptr, bufA, bufC, N, 0);
    // h1 = selu(mean_agg(t1) + r1 + b1) -> bufB
    prop_kernel<64, false, 1><<<nb_node, 256, 0, stream>>>(bufA, bufB, row_ptr, csr_src, dis, cnt_inv, bufC, b1, N);
    // [t2|r2+b2] = h1 @ [Wl2|Wr2]  (t2 -> bufA (N x 40), r2 -> bufC (N x 40))
    gemm_kernel<80, 5><<<nb_gemm, 256, 0, stream>>>(bufB, Wl2, Wr2, b2, bufA, bufC, N, 1);
    // out = softmax(mean_agg(t2) + r2)
    prop_kernel<40, false, 2><<<nb_node, 256, 0, stream>>>(bufA, out, row_ptr, csr_src, dis, cnt_inv, bufC, nullptr, N);
}

// Round 5
// 491.490 us; speedup vs baseline: 1.8017x; 1.8017x over previous
//
#include <hip/hip_runtime.h>
#include <hip/hip_bf16.h>
#include <math.h>

// Node classifier: KProp(K=2, gcn_norm) -> SAGEConv(64->64)+selu -> SAGEConv(64->40) -> softmax
// N=100000, E=1600000, D=H=64, C=40. All fp32.
//
// R5 structure:
//   CSR build with BLOCK-PRIVATE write streams (fix for R4's cross-XCD line thrash):
//     partition: each block counts its edge chunk per bucket (dst>>10, 98 buckets) in
//       LDS, reserves one contiguous segment per bucket via a single atomicAdd, then
//       writes its edges densely into private segments (each 64B line owned by 1 block).
//     bucket_base: tiny scan over bucket counts.
//     bucket_csr: one workgroup per bucket; LDS deg count + block scan -> row_ptr/dis/
//       cnt_inv (replaces 3 global scan kernels); fine scatter into the bucket's
//       ~65KB csr window (single-CU private -> L2 resident, full-line writebacks).
//   Props: float4 gathers (16 lanes x 4 edges per wave-instr, 16 edges unrolled),
//   cross-group shfl_xor reduce. 40-wide softmax pass keeps the scalar path.

#define RFL(x) __builtin_amdgcn_readfirstlane(x)
#define NSHIFT 10          // nodes per bucket = 1024
#define MAXBUCK 256        // LDS array bound in partition kernel

// ---------------- CSR build ----------------

__global__ void init_bcursor_kernel(int* __restrict__ bcursor, int nbuck, int cap) {
    int i = blockIdx.x * blockDim.x + threadIdx.x;
    if (i < nbuck) bcursor[i] = i * cap;
}

// Phase 1: block-private bucket partition.
__global__ __launch_bounds__(256) void partition_kernel(const int* __restrict__ src,
                                                        const int* __restrict__ dst,
                                                        int* __restrict__ bcursor,
                                                        int2* __restrict__ temp,
                                                        int e, int nbuck, int cap) {
    __shared__ int bc[MAXBUCK];    // counts, then running cursors
    __shared__ int gof_unused;     // (kept minimal)
    int t = threadIdx.x;
    int chunk = (e + gridDim.x - 1) / gridDim.x;
    int base = blockIdx.x * chunk;
    int cnt = e - base;
    if (cnt > chunk) cnt = chunk;
    if (cnt < 0) cnt = 0;
    for (int j = t; j < nbuck; j += 256) bc[j] = 0;
    __syncthreads();
    for (int i = t; i < cnt; i += 256) {
        int d = dst[base + i];
        atomicAdd(&bc[d >> NSHIFT], 1);
    }
    __syncthreads();
    // reserve private segments; bc becomes the block-local running cursor
    for (int j = t; j < nbuck; j += 256) {
        int c = bc[j];
        bc[j] = (c > 0) ? atomicAdd(&bcursor[j], c) : 0;
    }
    __syncthreads();
    for (int i = t; i < cnt; i += 256) {
        int s = src[base + i];
        int d = dst[base + i];
        int bk = d >> NSHIFT;
        int p = atomicAdd(&bc[bk], 1);
        if (p < (bk + 1) * cap) temp[p] = make_int2(s, d);
    }
}

// Tiny exclusive scan over bucket counts -> bbase; also row_ptr[n] = e.
__global__ __launch_bounds__(1024) void bucket_base_kernel(const int* __restrict__ bcursor,
                                                           int* __restrict__ bbase,
                                                           int* __restrict__ row_ptr,
                                                           int nbuck, int cap, int n, int e) {
    __shared__ int tmp[1024];
    int t = threadIdx.x;
    int v = (t < nbuck) ? (bcursor[t] - t * cap) : 0;
    tmp[t] = v;
    __syncthreads();
    for (int off = 1; off < 1024; off <<= 1) {
        int u = (t >= off) ? tmp[t - off] : 0;
        __syncthreads();
        tmp[t] += u;
        __syncthreads();
    }
    if (t < nbuck) bbase[t] = tmp[t] - v;   // exclusive
    if (t == 0) row_ptr[n] = e;
}

// Phase 2: per-bucket deg/row_ptr/dis/cnt_inv + fine scatter. One WG per bucket.
__global__ __launch_bounds__(256) void bucket_csr_kernel(const int2* __restrict__ temp,
                                                         const int* __restrict__ bcursor,
                                                         const int* __restrict__ bbase_arr,
                                                         int* __restrict__ row_ptr,
                                                         float* __restrict__ dis,
                                                         float* __restrict__ cnt_inv,
                                                         int* __restrict__ csr,
                                                         int n, int cap) {
    __shared__ int sdeg[1024];
    __shared__ int part[256];
    int b = blockIdx.x;
    int t = threadIdx.x;
    int nbeg = b << NSHIFT;
    int cnt = bcursor[b] - b * cap;
    if (cnt > cap) cnt = cap;
    int bbase = bbase_arr[b];
    const int2* tb = temp + (size_t)b * cap;
    for (int i = t; i < 1024; i += 256) sdeg[i] = 0;
    __syncthreads();
    for (int i = t; i < cnt; i += 256) {
        int d = tb[i].y;
        atomicAdd(&sdeg[d - nbeg], 1);
    }
    __syncthreads();
    int base4 = t * 4;
    int d0 = sdeg[base4 + 0], d1 = sdeg[base4 + 1], d2 = sdeg[base4 + 2], d3 = sdeg[base4 + 3];
    int run = d0 + d1 + d2 + d3;
    part[t] = run;
    __syncthreads();
    for (int off = 1; off < 256; off <<= 1) {
        int u = (t >= off) ? part[t - off] : 0;
        __syncthreads();
        part[t] += u;
        __syncthreads();
    }
    int ex = part[t] - run;   // exclusive offset of this thread's 4 nodes
    int o0 = ex, o1 = ex + d0, o2 = ex + d0 + d1, o3 = ex + d0 + d1 + d2;
    sdeg[base4 + 0] = o0; sdeg[base4 + 1] = o1; sdeg[base4 + 2] = o2; sdeg[base4 + 3] = o3;
    // per-node outputs
    int dd[4] = {d0, d1, d2, d3};
    int oo[4] = {o0, o1, o2, o3};
#pragma unroll
    for (int k = 0; k < 4; ++k) {
        int node = nbeg + base4 + k;
        if (node < n) {
            row_ptr[node] = bbase + oo[k];
            float fd = (float)dd[k];
            dis[node] = (dd[k] > 0) ? rsqrtf(fd) : 0.0f;
            cnt_inv[node] = 1.0f / fmaxf(fd, 1.0f);
        }
    }
    __syncthreads();
    // fine scatter within the bucket's private csr window
    for (int i = t; i < cnt; i += 256) {
        int2 ed = tb[i];
        int pos = atomicAdd(&sdeg[ed.y - nbeg], 1);
        csr[bbase + pos] = ed.x;
    }
}

// ---------------- propagation, float4 path (64-wide rows) ----------------
// Wave per node. lane = g*16 + l: edge slot g (0..3), feature quad l (0..15).
// EPI: 0 plain scale; 1 selu(acc*sc + r + b).
template <bool USE_W, int EPI>
__global__ __launch_bounds__(256) void prop4_kernel(const float4* __restrict__ in4,
                                                    float4* __restrict__ out4,
                                                    const int* __restrict__ row_ptr,
                                                    const int* __restrict__ csr_src,
                                                    const float* __restrict__ dis,
                                                    const float* __restrict__ nscale,
                                                    const float4* __restrict__ r4,
                                                    const float4* __restrict__ b4,
                                                    int n) {
    int lane = threadIdx.x & 63;
    int g = lane >> 4;
    int l = lane & 15;
    int node = RFL(blockIdx.x * 4 + (threadIdx.x >> 6));
    if (node >= n) return;
    int beg = row_ptr[node];
    int end = row_ptr[node + 1];
    float4 acc = make_float4(0.f, 0.f, 0.f, 0.f);
    int j = beg;
    // main: 16 edges per iteration (4 float4 gathers in flight per wave)
    for (; j + 16 <= end; j += 16) {
        int s[4];
        float4 v[4];
        float w[4];
#pragma unroll
        for (int q = 0; q < 4; ++q) s[q] = csr_src[j + q * 4 + g];
#pragma unroll
        for (int q = 0; q < 4; ++q) v[q] = in4[(size_t)s[q] * 16 + l];
#pragma unroll
        for (int q = 0; q < 4; ++q) w[q] = USE_W ? dis[s[q]] : 1.0f;
#pragma unroll
        for (int q = 0; q < 4; ++q) {
            acc.x += w[q] * v[q].x;
            acc.y += w[q] * v[q].y;
            acc.z += w[q] * v[q].z;
            acc.w += w[q] * v[q].w;
        }
    }
    // tail: 4 edges per iteration, masked
    for (; j < end; j += 4) {
        int idx = j + g;
        bool valid = idx < end;
        int s = csr_src[valid ? idx : (end - 1)];
        float w = USE_W ? dis[s] : 1.0f;
        if (!valid) w = 0.0f;
        float4 v = in4[(size_t)s * 16 + l];
        acc.x += w * v.x;
        acc.y += w * v.y;
        acc.z += w * v.z;
        acc.w += w * v.w;
    }
    // reduce the 4 edge-slot groups
    acc.x += __shfl_xor(acc.x, 16); acc.x += __shfl_xor(acc.x, 32);
    acc.y += __shfl_xor(acc.y, 16); acc.y += __shfl_xor(acc.y, 32);
    acc.z += __shfl_xor(acc.z, 16); acc.z += __shfl_xor(acc.z, 32);
    acc.w += __shfl_xor(acc.w, 16); acc.w += __shfl_xor(acc.w, 32);
    if (g == 0) {
        float sc = nscale[node];
        float4 r = make_float4(acc.x * sc, acc.y * sc, acc.z * sc, acc.w * sc);
        if (EPI == 1) {
            float4 ra = r4[(size_t)node * 16 + l];
            float4 bb = b4[l];
            const float scale = 1.0507009873554805f;
            const float alpha = 1.6732632423543772f;
            float t0 = r.x + ra.x + bb.x;
            float t1 = r.y + ra.y + bb.y;
            float t2 = r.z + ra.z + bb.z;
            float t3 = r.w + ra.w + bb.w;
            r.x = scale * (t0 > 0.0f ? t0 : alpha * expm1f(t0));
            r.y = scale * (t1 > 0.0f ? t1 : alpha * expm1f(t1));
            r.z = scale * (t2 > 0.0f ? t2 : alpha * expm1f(t2));
            r.w = scale * (t3 > 0.0f ? t3 : alpha * expm1f(t3));
        }
        out4[(size_t)node * 16 + l] = r;
    }
}

// ---------------- 40-wide softmax prop (scalar path) ----------------
__global__ __launch_bounds__(256) void prop_softmax_kernel(const float* __restrict__ in,
                                                           float* __restrict__ out,
                                                           const int* __restrict__ row_ptr,
                                                           const int* __restrict__ csr_src,
                                                           const float* __restrict__ nscale,
                                                           const float* __restrict__ r_add,
                                                           int n) {
    int lane = threadIdx.x & 63;
    int node = RFL(blockIdx.x * 4 + (threadIdx.x >> 6));
    if (node >= n) return;
    int beg = row_ptr[node];
    int end = row_ptr[node + 1];
    float acc = 0.0f;
    int j = beg;
    for (; j + 8 <= end; j += 8) {
        int s[8];
        float v[8];
#pragma unroll
        for (int q = 0; q < 8; ++q) s[q] = csr_src[j + q];
#pragma unroll
        for (int q = 0; q < 8; ++q) v[q] = in[(size_t)s[q] * 40 + lane];
#pragma unroll
        for (int q = 0; q < 8; ++q) acc += v[q];
    }
    for (; j < end; ++j) {
        acc += in[(size_t)csr_src[j] * 40 + lane];
    }
    float t = acc * nscale[node] + ((lane < 40) ? r_add[(size_t)node * 40 + lane] : 0.0f);
    float x = (lane < 40) ? t : -INFINITY;
    float m = x;
    for (int off = 32; off; off >>= 1) m = fmaxf(m, __shfl_xor(m, off));
    float e = (lane < 40) ? __expf(x - m) : 0.0f;
    float s = e;
    for (int off = 32; off; off >>= 1) s += __shfl_xor(s, off);
    if (lane < 40) out[(size_t)node * 40 + lane] = e / s;
}

// ---------------- tiled GEMM: [outL|outR] = in(64) @ [Wl|Wr] ----------------
template <int OC, int CP>
__global__ __launch_bounds__(256) void gemm_kernel(const float* __restrict__ in,
                                                   const float* __restrict__ Wl,
                                                   const float* __restrict__ Wr,
                                                   const float* __restrict__ bias,
                                                   float* __restrict__ outL,
                                                   float* __restrict__ outR,
                                                   int n, int add_bias) {
    constexpr int HC = OC / 2;
    constexpr int TX = OC / CP;
    constexpr int TY = 256 / TX;
    constexpr int NPT = 64 / TY;
    constexpr int XP = 68;
    constexpr int WP = OC + 4;
    __shared__ float sXT[64 * XP];
    __shared__ float sW[64 * WP];
    int t = threadIdx.x;
    int blk = blockIdx.x;
    for (int i = 0; i < 16; ++i) {
        int idx = i * 256 + t;
        int nd = idx >> 6;
        int k = idx & 63;
        int ng = blk * 64 + nd;
        float v = in[(size_t)(ng < n ? ng : n - 1) * 64 + k];
        sXT[k * XP + nd] = v;
    }
    for (int i = t; i < 64 * HC; i += 256) {
        int k = i / HC;
        int c = i % HC;
        sW[k * WP + c] = Wl[i];
        sW[k * WP + HC + c] = Wr[i];
    }
    __syncthreads();
    int tx = t % TX;
    int ty = t / TX;
    float acc[NPT][CP];
#pragma unroll
    for (int i = 0; i < NPT; ++i)
#pragma unroll
        for (int c = 0; c < CP; ++c) acc[i][c] = 0.0f;
#pragma unroll 4
    for (int k = 0; k < 64; ++k) {
        float xv[NPT];
#pragma unroll
        for (int i = 0; i < NPT; ++i) xv[i] = sXT[k * XP + ty * NPT + i];
        float wv[CP];
#pragma unroll
        for (int c = 0; c < CP; ++c) wv[c] = sW[k * WP + tx * CP + c];
#pragma unroll
        for (int i = 0; i < NPT; ++i)
#pragma unroll
            for (int c = 0; c < CP; ++c) acc[i][c] += xv[i] * wv[c];
    }
#pragma unroll
    for (int i = 0; i < NPT; ++i) {
        int ng = blk * 64 + ty * NPT + i;
        if (ng >= n) break;
#pragma unroll
        for (int c = 0; c < CP; ++c) {
            int col = tx * CP + c;
            if (col < HC) {
                outL[(size_t)ng * HC + col] = acc[i][c];
            } else {
                float v = acc[i][c] + (add_bias ? bias[col - HC] : 0.0f);
                outR[(size_t)ng * HC + (col - HC)] = v;
            }
        }
    }
}

// ---------------- launch ----------------

extern "C" void kernel_launch(void* const* d_in, const int* in_sizes, int n_in,
                              void* d_out, int out_size, void* d_ws, size_t ws_size,
                              hipStream_t stream) {
    const float* x   = (const float*)d_in[0];
    const float* Wl1 = (const float*)d_in[1];
    const float* Wr1 = (const float*)d_in[2];
    const float* b1  = (const float*)d_in[3];
    const float* Wl2 = (const float*)d_in[4];
    const float* Wr2 = (const float*)d_in[5];
    const float* b2  = (const float*)d_in[6];
    const int* edge_src = (const int*)d_in[7];
    const int* edge_dst = (const int*)d_in[8];
    float* out = (float*)d_out;

    const int N = in_sizes[0] / 64;
    const int E = in_sizes[7];
    const int NBUCK = (N + (1 << NSHIFT) - 1) >> NSHIFT;   // 98
    // per-bucket fixed-capacity region in temp; clamp so temp fits bufC
    size_t bufC_bytes = (size_t)N * 64 * 4;
    int cap = E / NBUCK + E / (2 * NBUCK) + 1024;          // mean + 50% + slack
    int cap_max = (int)(bufC_bytes / ((size_t)NBUCK * 8));
    if (cap > cap_max) cap = cap_max;

    size_t off = 0;
    auto carve = [&](size_t bytes) -> void* {
        void* p = (char*)d_ws + off;
        off = (off + bytes + 255) & ~(size_t)255;
        return p;
    };
    int*   row_ptr = (int*)carve((size_t)(N + 1) * 4);
    int*   bcursor = (int*)carve((size_t)NBUCK * 4);
    int*   bbase   = (int*)carve((size_t)NBUCK * 4);
    float* dis     = (float*)carve((size_t)N * 4);
    float* cnt_inv = (float*)carve((size_t)N * 4);
    int*   csr_src = (int*)carve((size_t)E * 4);
    float* bufA    = (float*)carve((size_t)N * 64 * 4);
    float* bufB    = (float*)carve((size_t)N * 64 * 4);
    float* bufC    = (float*)carve(bufC_bytes);
    int2*  temp    = (int2*)bufC;                          // alias: dead before bufC written
    (void)ws_size;

    const int nb_node = (N + 3) / 4;
    const int nb_gemm = (N + 63) / 64;

    // CSR build
    init_bcursor_kernel<<<(NBUCK + 255) / 256, 256, 0, stream>>>(bcursor, NBUCK, cap);
    partition_kernel<<<256, 256, 0, stream>>>(edge_src, edge_dst, bcursor, temp, E, NBUCK, cap);
    bucket_base_kernel<<<1, 1024, 0, stream>>>(bcursor, bbase, row_ptr, NBUCK, cap, N, E);
    bucket_csr_kernel<<<NBUCK, 256, 0, stream>>>(temp, bcursor, bbase, row_ptr, dis, cnt_inv,
                                                 csr_src, N, cap);

    // KProp x2: h = S (S x)
    prop4_kernel<true, 0><<<nb_node, 256, 0, stream>>>((const float4*)x, (float4*)bufA,
                                                       row_ptr, csr_src, dis, dis, nullptr, nullptr, N);
    prop4_kernel<true, 0><<<nb_node, 256, 0, stream>>>((const float4*)bufA, (float4*)bufB,
                                                       row_ptr, csr_src, dis, dis, nullptr, nullptr, N);
    // [t1|r1] = h @ [Wl1|Wr1]  (t1 -> bufA, r1 -> bufC)
    gemm_kernel<128, 8><<<nb_gemm, 256, 0, stream>>>(bufB, Wl1, Wr1, nullptr, bufA, bufC, N, 0);
    // h1 = selu(mean_agg(t1) + r1 + b1) -> bufB
    prop4_kernel<false, 1><<<nb_node, 256, 0, stream>>>((const float4*)bufA, (float4*)bufB,
                                                        row_ptr, csr_src, dis, cnt_inv,
                                                        (const float4*)bufC, (const float4*)b1, N);
    // [t2|r2+b2] = h1 @ [Wl2|Wr2]  (t2 -> bufA (N x 40), r2 -> bufC (N x 40))
    gemm_kernel<80, 5><<<nb_gemm, 256, 0, stream>>>(bufB, Wl2, Wr2, b2, bufA, bufC, N, 1);
    // out = softmax(mean_agg(t2) + r2)
    prop_softmax_kernel<<<nb_node, 256, 0, stream>>>(bufA, out, row_ptr, csr_src, cnt_inv, bufC, N);
}

// Round 6
// 485.220 us; speedup vs baseline: 1.8250x; 1.0129x over previous
//
#include <hip/hip_runtime.h>
#include <hip/hip_bf16.h>
#include <math.h>

// Node classifier: KProp(K=2, gcn_norm) -> SAGEConv(64->64)+selu -> SAGEConv(64->40) -> softmax
// N=100000, E=1600000, D=H=64, C=40. All fp32.
//
// R6 = R5 with:
//   - prop_softmax: 16-deep gather unroll (was 8)
//   - prop4: extra 8-edge rung in the unroll ladder (tail MLP)
//   - bucket_base folded into bucket_csr (one fewer kernel)
// CSR build keeps R5's block-private write streams (no cross-XCD line thrash).

#define RFL(x) __builtin_amdgcn_readfirstlane(x)
#define NSHIFT 10          // nodes per bucket = 1024
#define MAXBUCK 256        // LDS array bound in partition kernel

// ---------------- CSR build ----------------

__global__ void init_bcursor_kernel(int* __restrict__ bcursor, int nbuck, int cap) {
    int i = blockIdx.x * blockDim.x + threadIdx.x;
    if (i < nbuck) bcursor[i] = i * cap;
}

// Phase 1: block-private bucket partition.
__global__ __launch_bounds__(256) void partition_kernel(const int* __restrict__ src,
                                                        const int* __restrict__ dst,
                                                        int* __restrict__ bcursor,
                                                        int2* __restrict__ temp,
                                                        int e, int nbuck, int cap) {
    __shared__ int bc[MAXBUCK];    // counts, then running cursors
    int t = threadIdx.x;
    int chunk = (e + gridDim.x - 1) / gridDim.x;
    int base = blockIdx.x * chunk;
    int cnt = e - base;
    if (cnt > chunk) cnt = chunk;
    if (cnt < 0) cnt = 0;
    for (int j = t; j < nbuck; j += 256) bc[j] = 0;
    __syncthreads();
    for (int i = t; i < cnt; i += 256) {
        int d = dst[base + i];
        atomicAdd(&bc[d >> NSHIFT], 1);
    }
    __syncthreads();
    // reserve private segments; bc becomes the block-local running cursor
    for (int j = t; j < nbuck; j += 256) {
        int c = bc[j];
        bc[j] = (c > 0) ? atomicAdd(&bcursor[j], c) : 0;
    }
    __syncthreads();
    for (int i = t; i < cnt; i += 256) {
        int s = src[base + i];
        int d = dst[base + i];
        int bk = d >> NSHIFT;
        int p = atomicAdd(&bc[bk], 1);
        if (p < (bk + 1) * cap) temp[p] = make_int2(s, d);
    }
}

// Phase 2: per-bucket bbase prefix + deg/row_ptr/dis/cnt_inv + fine scatter.
// One WG per bucket. (bucket_base kernel folded in: each block scans bcursor.)
__global__ __launch_bounds__(256) void bucket_csr_kernel(const int2* __restrict__ temp,
                                                         const int* __restrict__ bcursor,
                                                         int* __restrict__ row_ptr,
                                                         float* __restrict__ dis,
                                                         float* __restrict__ cnt_inv,
                                                         int* __restrict__ csr,
                                                         int n, int cap, int nbuck, int e) {
    __shared__ int sdeg[1024];
    __shared__ int part[256];
    int b = blockIdx.x;
    int t = threadIdx.x;
    int nbeg = b << NSHIFT;
    // ---- compute bbase = sum of counts of buckets < b (small LDS scan) ----
    int cj = 0;
    if (t < nbuck) {
        cj = bcursor[t] - t * cap;
        if (cj > cap) cj = cap;
    }
    part[t] = cj;
    __syncthreads();
    for (int off = 1; off < 256; off <<= 1) {
        int u = (t >= off) ? part[t - off] : 0;
        __syncthreads();
        part[t] += u;
        __syncthreads();
    }
    int cntb = bcursor[b] - b * cap;
    if (cntb > cap) cntb = cap;
    int bbase = part[b] - cntb;   // exclusive prefix at b
    if (b == 0 && t == 0) row_ptr[n] = e;
    __syncthreads();
    int cnt = cntb;
    const int2* tb = temp + (size_t)b * cap;
    for (int i = t; i < 1024; i += 256) sdeg[i] = 0;
    __syncthreads();
    for (int i = t; i < cnt; i += 256) {
        int d = tb[i].y;
        atomicAdd(&sdeg[d - nbeg], 1);
    }
    __syncthreads();
    int base4 = t * 4;
    int d0 = sdeg[base4 + 0], d1 = sdeg[base4 + 1], d2 = sdeg[base4 + 2], d3 = sdeg[base4 + 3];
    int run = d0 + d1 + d2 + d3;
    part[t] = run;
    __syncthreads();
    for (int off = 1; off < 256; off <<= 1) {
        int u = (t >= off) ? part[t - off] : 0;
        __syncthreads();
        part[t] += u;
        __syncthreads();
    }
    int ex = part[t] - run;   // exclusive offset of this thread's 4 nodes
    int o0 = ex, o1 = ex + d0, o2 = ex + d0 + d1, o3 = ex + d0 + d1 + d2;
    sdeg[base4 + 0] = o0; sdeg[base4 + 1] = o1; sdeg[base4 + 2] = o2; sdeg[base4 + 3] = o3;
    int dd[4] = {d0, d1, d2, d3};
    int oo[4] = {o0, o1, o2, o3};
#pragma unroll
    for (int k = 0; k < 4; ++k) {
        int node = nbeg + base4 + k;
        if (node < n) {
            row_ptr[node] = bbase + oo[k];
            float fd = (float)dd[k];
            dis[node] = (dd[k] > 0) ? rsqrtf(fd) : 0.0f;
            cnt_inv[node] = 1.0f / fmaxf(fd, 1.0f);
        }
    }
    __syncthreads();
    // fine scatter within the bucket's private csr window
    for (int i = t; i < cnt; i += 256) {
        int2 ed = tb[i];
        int pos = atomicAdd(&sdeg[ed.y - nbeg], 1);
        csr[bbase + pos] = ed.x;
    }
}

// ---------------- propagation, float4 path (64-wide rows) ----------------
// Wave per node. lane = g*16 + l: edge slot g (0..3), feature quad l (0..15).
// EPI: 0 plain scale; 1 selu(acc*sc + r + b).
template <bool USE_W, int EPI>
__global__ __launch_bounds__(256) void prop4_kernel(const float4* __restrict__ in4,
                                                    float4* __restrict__ out4,
                                                    const int* __restrict__ row_ptr,
                                                    const int* __restrict__ csr_src,
                                                    const float* __restrict__ dis,
                                                    const float* __restrict__ nscale,
                                                    const float4* __restrict__ r4,
                                                    const float4* __restrict__ b4,
                                                    int n) {
    int lane = threadIdx.x & 63;
    int g = lane >> 4;
    int l = lane & 15;
    int node = RFL(blockIdx.x * 4 + (threadIdx.x >> 6));
    if (node >= n) return;
    int beg = row_ptr[node];
    int end = row_ptr[node + 1];
    float4 acc = make_float4(0.f, 0.f, 0.f, 0.f);
    int j = beg;
    // 16 edges per iteration (4 float4 gathers in flight per lane)
    for (; j + 16 <= end; j += 16) {
        int s[4];
        float4 v[4];
        float w[4];
#pragma unroll
        for (int q = 0; q < 4; ++q) s[q] = csr_src[j + q * 4 + g];
#pragma unroll
        for (int q = 0; q < 4; ++q) v[q] = in4[(size_t)s[q] * 16 + l];
#pragma unroll
        for (int q = 0; q < 4; ++q) w[q] = USE_W ? dis[s[q]] : 1.0f;
#pragma unroll
        for (int q = 0; q < 4; ++q) {
            acc.x += w[q] * v[q].x;
            acc.y += w[q] * v[q].y;
            acc.z += w[q] * v[q].z;
            acc.w += w[q] * v[q].w;
        }
    }
    // 8-edge rung
    for (; j + 8 <= end; j += 8) {
        int s[2];
        float4 v[2];
        float w[2];
#pragma unroll
        for (int q = 0; q < 2; ++q) s[q] = csr_src[j + q * 4 + g];
#pragma unroll
        for (int q = 0; q < 2; ++q) v[q] = in4[(size_t)s[q] * 16 + l];
#pragma unroll
        for (int q = 0; q < 2; ++q) w[q] = USE_W ? dis[s[q]] : 1.0f;
#pragma unroll
        for (int q = 0; q < 2; ++q) {
            acc.x += w[q] * v[q].x;
            acc.y += w[q] * v[q].y;
            acc.z += w[q] * v[q].z;
            acc.w += w[q] * v[q].w;
        }
    }
    // tail: 4 edges per iteration, masked
    for (; j < end; j += 4) {
        int idx = j + g;
        bool valid = idx < end;
        int s = csr_src[valid ? idx : (end - 1)];
        float w = USE_W ? dis[s] : 1.0f;
        if (!valid) w = 0.0f;
        float4 v = in4[(size_t)s * 16 + l];
        acc.x += w * v.x;
        acc.y += w * v.y;
        acc.z += w * v.z;
        acc.w += w * v.w;
    }
    // reduce the 4 edge-slot groups
    acc.x += __shfl_xor(acc.x, 16); acc.x += __shfl_xor(acc.x, 32);
    acc.y += __shfl_xor(acc.y, 16); acc.y += __shfl_xor(acc.y, 32);
    acc.z += __shfl_xor(acc.z, 16); acc.z += __shfl_xor(acc.z, 32);
    acc.w += __shfl_xor(acc.w, 16); acc.w += __shfl_xor(acc.w, 32);
    if (g == 0) {
        float sc = nscale[node];
        float4 r = make_float4(acc.x * sc, acc.y * sc, acc.z * sc, acc.w * sc);
        if (EPI == 1) {
            float4 ra = r4[(size_t)node * 16 + l];
            float4 bb = b4[l];
            const float scale = 1.0507009873554805f;
            const float alpha = 1.6732632423543772f;
            float t0 = r.x + ra.x + bb.x;
            float t1 = r.y + ra.y + bb.y;
            float t2 = r.z + ra.z + bb.z;
            float t3 = r.w + ra.w + bb.w;
            r.x = scale * (t0 > 0.0f ? t0 : alpha * expm1f(t0));
            r.y = scale * (t1 > 0.0f ? t1 : alpha * expm1f(t1));
            r.z = scale * (t2 > 0.0f ? t2 : alpha * expm1f(t2));
            r.w = scale * (t3 > 0.0f ? t3 : alpha * expm1f(t3));
        }
        out4[(size_t)node * 16 + l] = r;
    }
}

// ---------------- 40-wide softmax prop (scalar path, 16-deep unroll) ----------------
__global__ __launch_bounds__(256) void prop_softmax_kernel(const float* __restrict__ in,
                                                           float* __restrict__ out,
                                                           const int* __restrict__ row_ptr,
                                                           const int* __restrict__ csr_src,
                                                           const float* __restrict__ nscale,
                                                           const float* __restrict__ r_add,
                                                           int n) {
    int lane = threadIdx.x & 63;
    int node = RFL(blockIdx.x * 4 + (threadIdx.x >> 6));
    if (node >= n) return;
    int beg = row_ptr[node];
    int end = row_ptr[node + 1];
    float acc = 0.0f;
    int j = beg;
    for (; j + 16 <= end; j += 16) {
        int s[16];
        float v[16];
#pragma unroll
        for (int q = 0; q < 16; ++q) s[q] = csr_src[j + q];
#pragma unroll
        for (int q = 0; q < 16; ++q) v[q] = in[(size_t)s[q] * 40 + lane];
#pragma unroll
        for (int q = 0; q < 16; ++q) acc += v[q];
    }
    for (; j + 8 <= end; j += 8) {
        int s[8];
        float v[8];
#pragma unroll
        for (int q = 0; q < 8; ++q) s[q] = csr_src[j + q];
#pragma unroll
        for (int q = 0; q < 8; ++q) v[q] = in[(size_t)s[q] * 40 + lane];
#pragma unroll
        for (int q = 0; q < 8; ++q) acc += v[q];
    }
    for (; j < end; ++j) {
        acc += in[(size_t)csr_src[j] * 40 + lane];
    }
    float t = acc * nscale[node] + ((lane < 40) ? r_add[(size_t)node * 40 + lane] : 0.0f);
    float x = (lane < 40) ? t : -INFINITY;
    float m = x;
    for (int off = 32; off; off >>= 1) m = fmaxf(m, __shfl_xor(m, off));
    float e = (lane < 40) ? __expf(x - m) : 0.0f;
    float s = e;
    for (int off = 32; off; off >>= 1) s += __shfl_xor(s, off);
    if (lane < 40) out[(size_t)node * 40 + lane] = e / s;
}

// ---------------- tiled GEMM: [outL|outR] = in(64) @ [Wl|Wr] ----------------
template <int OC, int CP>
__global__ __launch_bounds__(256) void gemm_kernel(const float* __restrict__ in,
                                                   const float* __restrict__ Wl,
                                                   const float* __restrict__ Wr,
                                                   const float* __restrict__ bias,
                                                   float* __restrict__ outL,
                                                   float* __restrict__ outR,
                                                   int n, int add_bias) {
    constexpr int HC = OC / 2;
    constexpr int TX = OC / CP;
    constexpr int TY = 256 / TX;
    constexpr int NPT = 64 / TY;
    constexpr int XP = 68;
    constexpr int WP = OC + 4;
    __shared__ float sXT[64 * XP];
    __shared__ float sW[64 * WP];
    int t = threadIdx.x;
    int blk = blockIdx.x;
    for (int i = 0; i < 16; ++i) {
        int idx = i * 256 + t;
        int nd = idx >> 6;
        int k = idx & 63;
        int ng = blk * 64 + nd;
        float v = in[(size_t)(ng < n ? ng : n - 1) * 64 + k];
        sXT[k * XP + nd] = v;
    }
    for (int i = t; i < 64 * HC; i += 256) {
        int k = i / HC;
        int c = i % HC;
        sW[k * WP + c] = Wl[i];
        sW[k * WP + HC + c] = Wr[i];
    }
    __syncthreads();
    int tx = t % TX;
    int ty = t / TX;
    float acc[NPT][CP];
#pragma unroll
    for (int i = 0; i < NPT; ++i)
#pragma unroll
        for (int c = 0; c < CP; ++c) acc[i][c] = 0.0f;
#pragma unroll 4
    for (int k = 0; k < 64; ++k) {
        float xv[NPT];
#pragma unroll
        for (int i = 0; i < NPT; ++i) xv[i] = sXT[k * XP + ty * NPT + i];
        float wv[CP];
#pragma unroll
        for (int c = 0; c < CP; ++c) wv[c] = sW[k * WP + tx * CP + c];
#pragma unroll
        for (int i = 0; i < NPT; ++i)
#pragma unroll
            for (int c = 0; c < CP; ++c) acc[i][c] += xv[i] * wv[c];
    }
#pragma unroll
    for (int i = 0; i < NPT; ++i) {
        int ng = blk * 64 + ty * NPT + i;
        if (ng >= n) break;
#pragma unroll
        for (int c = 0; c < CP; ++c) {
            int col = tx * CP + c;
            if (col < HC) {
                outL[(size_t)ng * HC + col] = acc[i][c];
            } else {
                float v = acc[i][c] + (add_bias ? bias[col - HC] : 0.0f);
                outR[(size_t)ng * HC + (col - HC)] = v;
            }
        }
    }
}

// ---------------- launch ----------------

extern "C" void kernel_launch(void* const* d_in, const int* in_sizes, int n_in,
                              void* d_out, int out_size, void* d_ws, size_t ws_size,
                              hipStream_t stream) {
    const float* x   = (const float*)d_in[0];
    const float* Wl1 = (const float*)d_in[1];
    const float* Wr1 = (const float*)d_in[2];
    const float* b1  = (const float*)d_in[3];
    const float* Wl2 = (const float*)d_in[4];
    const float* Wr2 = (const float*)d_in[5];
    const float* b2  = (const float*)d_in[6];
    const int* edge_src = (const int*)d_in[7];
    const int* edge_dst = (const int*)d_in[8];
    float* out = (float*)d_out;

    const int N = in_sizes[0] / 64;
    const int E = in_sizes[7];
    const int NBUCK = (N + (1 << NSHIFT) - 1) >> NSHIFT;   // 98
    size_t bufC_bytes = (size_t)N * 64 * 4;
    int cap = E / NBUCK + E / (2 * NBUCK) + 1024;          // mean + 50% + slack
    int cap_max = (int)(bufC_bytes / ((size_t)NBUCK * 8));
    if (cap > cap_max) cap = cap_max;

    size_t off = 0;
    auto carve = [&](size_t bytes) -> void* {
        void* p = (char*)d_ws + off;
        off = (off + bytes + 255) & ~(size_t)255;
        return p;
    };
    int*   row_ptr = (int*)carve((size_t)(N + 1) * 4);
    int*   bcursor = (int*)carve((size_t)NBUCK * 4);
    float* dis     = (float*)carve((size_t)N * 4);
    float* cnt_inv = (float*)carve((size_t)N * 4);
    int*   csr_src = (int*)carve((size_t)E * 4);
    float* bufA    = (float*)carve((size_t)N * 64 * 4);
    float* bufB    = (float*)carve((size_t)N * 64 * 4);
    float* bufC    = (float*)carve(bufC_bytes);
    int2*  temp    = (int2*)bufC;                          // alias: dead before bufC written
    (void)ws_size;

    const int nb_node = (N + 3) / 4;
    const int nb_gemm = (N + 63) / 64;

    // CSR build
    init_bcursor_kernel<<<(NBUCK + 255) / 256, 256, 0, stream>>>(bcursor, NBUCK, cap);
    partition_kernel<<<256, 256, 0, stream>>>(edge_src, edge_dst, bcursor, temp, E, NBUCK, cap);
    bucket_csr_kernel<<<NBUCK, 256, 0, stream>>>(temp, bcursor, row_ptr, dis, cnt_inv,
                                                 csr_src, N, cap, NBUCK, E);

    // KProp x2: h = S (S x)
    prop4_kernel<true, 0><<<nb_node, 256, 0, stream>>>((const float4*)x, (float4*)bufA,
                                                       row_ptr, csr_src, dis, dis, nullptr, nullptr, N);
    prop4_kernel<true, 0><<<nb_node, 256, 0, stream>>>((const float4*)bufA, (float4*)bufB,
                                                       row_ptr, csr_src, dis, dis, nullptr, nullptr, N);
    // [t1|r1] = h @ [Wl1|Wr1]  (t1 -> bufA, r1 -> bufC)
    gemm_kernel<128, 8><<<nb_gemm, 256, 0, stream>>>(bufB, Wl1, Wr1, nullptr, bufA, bufC, N, 0);
    // h1 = selu(mean_agg(t1) + r1 + b1) -> bufB
    prop4_kernel<false, 1><<<nb_node, 256, 0, stream>>>((const float4*)bufA, (float4*)bufB,
                                                        row_ptr, csr_src, dis, cnt_inv,
                                                        (const float4*)bufC, (const float4*)b1, N);
    // [t2|r2+b2] = h1 @ [Wl2|Wr2]  (t2 -> bufA (N x 40), r2 -> bufC (N x 40))
    gemm_kernel<80, 5><<<nb_gemm, 256, 0, stream>>>(bufB, Wl2, Wr2, b2, bufA, bufC, N, 1);
    // out = softmax(mean_agg(t2) + r2)
    prop_softmax_kernel<<<nb_node, 256, 0, stream>>>(bufA, out, row_ptr, csr_src, cnt_inv, bufC, N);
}